// Round 11
// baseline (254.888 us; speedup 1.0000x reference)
//
#include <hip/hip_runtime.h>
#include <stdint.h>

// Problem constants (B=8, S=1024, D=256, K=16384)
#define N_ROWS 8192
#define D_DIM  256
#define K_CENT 16384

typedef __attribute__((ext_vector_type(8))) short bf16x8;
typedef __attribute__((ext_vector_type(4))) float f32x4;

// Monotone order-preserving float->uint mapping (all dists finite)
__device__ __forceinline__ uint32_t fkey(float f) {
    uint32_t b = __float_as_uint(f);
    return (b & 0x80000000u) ? ~b : (b | 0x80000000u);
}

// f32 -> bf16 round-to-nearest-even
__device__ __forceinline__ unsigned short f2bf(float f) {
    uint32_t u = __float_as_uint(f);
    uint32_t r = u + 0x7FFFu + ((u >> 16) & 1u);
    return (unsigned short)(r >> 16);
}

__device__ __forceinline__ void gload_lds16(const void* g, void* l) {
    __builtin_amdgcn_global_load_lds(
        (const __attribute__((address_space(1))) void*)g,
        (__attribute__((address_space(3))) void*)l, 16, 0, 0);
}

// ---------------- prep: fused bf16 convert + norms (one wave per row) -------
__global__ __launch_bounds__(256)
void prep_kernel(const float* __restrict__ feat,
                 const float* __restrict__ cent,
                 unsigned short* __restrict__ Abf,
                 unsigned short* __restrict__ Bbf,
                 float* __restrict__ xnorm,
                 float* __restrict__ cnorm) {
    int gtid = blockIdx.x * blockDim.x + threadIdx.x;
    int wave = gtid >> 6;
    int lane = gtid & 63;
    if (wave >= N_ROWS + K_CENT) return;
    const float* src;
    unsigned short* dst;
    float* ndst;
    if (wave < N_ROWS) {
        src = feat + (size_t)wave * D_DIM;
        dst = Abf + (size_t)wave * D_DIM;
        ndst = xnorm + wave;
    } else {
        int r = wave - N_ROWS;
        src = cent + (size_t)r * D_DIM;
        dst = Bbf + (size_t)r * D_DIM;
        ndst = cnorm + r;
    }
    float4 v = ((const float4*)src)[lane];
    float s = v.x * v.x + v.y * v.y + v.z * v.z + v.w * v.w;
    ushort4 o;
    o.x = f2bf(v.x); o.y = f2bf(v.y); o.z = f2bf(v.z); o.w = f2bf(v.w);
    *(ushort4*)(dst + lane * 4) = o;
    #pragma unroll
    for (int off = 32; off >= 1; off >>= 1) s += __shfl_xor(s, off);
    if (lane == 0) *ndst = s;
}

// ------- A-resident streaming dist GEMM -------
// Grid: 64 row-tiles x 8 col-ranges. Block: 512 threads = 8 waves.
// Each wave owns 16 feature rows; their A fragments (16 rows x 256 dims)
// live in 32 VGPRs for the whole kernel. B streams through double-buffered
// LDS in 64-center tiles (32 KB: 8 k-slabs of [64 c][32 k]); dist is written
// continuously, one 128x64 stripe per tile.
#define TROWS 128
#define TCOLS 64
#define NT    32   // tiles per block (2048 centers per col-range)

__global__ __launch_bounds__(512, 4)
void dist_stream(const unsigned short* __restrict__ Abf,   // 8192 x 256 bf16
                 const unsigned short* __restrict__ Bbf,   // 16384 x 256 bf16
                 const float* __restrict__ xnorm,
                 const float* __restrict__ cnorm,
                 float* __restrict__ dist,                 // 8192 x 16384
                 float* __restrict__ blockmins) {          // 8192 x 256
    __shared__ unsigned short Bs[2][16384];   // 2 x 32KB

    const int tid = threadIdx.x;
    const int lane = tid & 63;
    const int w = tid >> 6;                 // row-group 0..7
    const int cl = lane & 15, kg = lane >> 4;
    const int row0 = blockIdx.x * TROWS;
    const int crange0 = blockIdx.y * (NT * TCOLS);   // 2048 centers per range

    const int row = row0 + w * 16 + cl;
    const float xn = xnorm[row];
    float* const drow = dist + (size_t)row * K_CENT;

    // A fragments resident in registers (validated round-5 fragment layout:
    // B-slot operand, col = lane&15 = cl, k = kg*8 + j within each 32-k step)
    bf16x8 af[8];
    #pragma unroll
    for (int ks = 0; ks < 8; ++ks)
        af[ks] = *(const bf16x8*)(Abf + (size_t)row * D_DIM + ks * 32 + kg * 8);

    // stage tile 0: chunk f -> (ks = f>>8, r = (f&255)>>2, kq = f&3)
    // LDS shorts offset = f*8 = ks*2048 + r*32 + kq*8 (8 slabs x 64 rows x 64B)
    #pragma unroll
    for (int j = 0; j < 4; ++j) {
        int f = tid + 512 * j;
        int ks = f >> 8, s = f & 255, r = s >> 2, kq = s & 3;
        gload_lds16(Bbf + (size_t)(crange0 + r) * D_DIM + ks * 32 + kq * 8,
                    &Bs[0][0] + f * 8);
    }
    __syncthreads();

    int buf = 0;
    for (int t = 0; t < NT; ++t) {
        const int col0 = crange0 + t * TCOLS;

        // prefetch next B tile into the alternate buffer
        if (t + 1 < NT) {
            #pragma unroll
            for (int j = 0; j < 4; ++j) {
                int f = tid + 512 * j;
                int ks = f >> 8, s = f & 255, r = s >> 2, kq = s & 3;
                gload_lds16(Bbf + (size_t)(col0 + TCOLS + r) * D_DIM + ks * 32 + kq * 8,
                            &Bs[buf ^ 1][0] + f * 8);
            }
        }

        // compute 16 rows x 64 centers (transposed C/D: lane -> row cl,
        // center cols kg*4+reg — validated round-5 mapping)
        f32x4 acc[4];
        #pragma unroll
        for (int c = 0; c < 4; ++c) acc[c] = (f32x4){0.f, 0.f, 0.f, 0.f};

        #pragma unroll
        for (int ks = 0; ks < 8; ++ks) {
            #pragma unroll
            for (int c = 0; c < 4; ++c) {
                bf16x8 b = *(const bf16x8*)
                    &Bs[buf][ks * 2048 + (c * 16 + cl) * 32 + kg * 8];
                acc[c] = __builtin_amdgcn_mfma_f32_16x16x32_bf16(
                    b, af[ks], acc[c], 0, 0, 0);
            }
        }

        // epilogue: continuous nontemporal dist stream + per-64col row min
        float rmin = 3.4e38f;
        #pragma unroll
        for (int c = 0; c < 4; ++c) {
            const int colb = col0 + c * 16 + kg * 4;
            float4 cn4 = *(const float4*)&cnorm[colb];
            f32x4 a = acc[c];
            f32x4 d4;
            d4[0] = (xn - 2.f * a[0]) + cn4.x;
            d4[1] = (xn - 2.f * a[1]) + cn4.y;
            d4[2] = (xn - 2.f * a[2]) + cn4.z;
            d4[3] = (xn - 2.f * a[3]) + cn4.w;
            __builtin_nontemporal_store(d4, (f32x4*)(drow + colb));
            rmin = fminf(rmin,
                   fminf(fminf(d4[0], d4[1]), fminf(d4[2], d4[3])));
        }
        // lanes {cl, cl+16, cl+32, cl+48} share this row
        rmin = fminf(rmin, __shfl_xor(rmin, 16));
        rmin = fminf(rmin, __shfl_xor(rmin, 32));
        if (kg == 0)
            blockmins[(size_t)row * 256 + blockIdx.y * NT + t] = rmin;

        __syncthreads();   // staged next tile complete; buffer free
        buf ^= 1;
    }
}

// -------- recheck: candidate COLUMNS via coalesced dist re-read ---------
// One wave per row; 4 rows per 256-thread block.
__global__ __launch_bounds__(256)
void recheck_finalize(const float* __restrict__ feat,
                      const float* __restrict__ cent,
                      const float* __restrict__ xnorm,
                      const float* __restrict__ cnorm,
                      const float* __restrict__ blockmins,
                      const float* __restrict__ dist,
                      float* __restrict__ quant,
                      float* __restrict__ ids) {
    __shared__ float bms[4][256];
    const int tid = threadIdx.x;
    const int wv = tid >> 6;
    const int lane = tid & 63;
    const int row = blockIdx.x * 4 + wv;

    float4 xv = ((const float4*)(feat + (size_t)row * D_DIM))[lane];
    float4 bm4 = ((const float4*)(blockmins + (size_t)row * 256))[lane];
    ((float4*)&bms[wv][0])[lane] = bm4;   // wave-private LDS region, no barrier

    float gmin = fminf(fminf(bm4.x, bm4.y), fminf(bm4.z, bm4.w));
    #pragma unroll
    for (int off = 32; off >= 1; off >>= 1)
        gmin = fminf(gmin, __shfl_xor(gmin, off));

    // worst-case |bf16dist - exactdist| <= ~0.13 ; 1.0 gives 7x margin
    const float thr = gmin + 1.0f;
    const float xn = xnorm[row];
    const float* drow = dist + (size_t)row * K_CENT;

    unsigned long long best = 0xFFFFFFFFFFFFFFFFull;
    for (int b = 0; b < 256; ++b) {
        if (bms[wv][b] <= thr) {                 // wave-uniform branch
            float d = drow[b * 64 + lane];       // coalesced 256B
            unsigned long long m = __ballot(d <= thr);
            while (m) {                          // wave-uniform candidate loop
                int l = __ffsll((unsigned long long)m) - 1;
                m &= m - 1;
                int c = b * 64 + l;
                float4 cv = ((const float4*)(cent + (size_t)c * D_DIM))[lane];
                float p = fmaf(xv.x, cv.x,
                          fmaf(xv.y, cv.y,
                          fmaf(xv.z, cv.z, xv.w * cv.w)));
                #pragma unroll
                for (int off = 32; off >= 1; off >>= 1)
                    p += __shfl_xor(p, off);     // pairwise tree sum
                float dd = (xn - 2.f * p) + cnorm[c];
                unsigned long long key =
                    ((unsigned long long)fkey(dd) << 32) | (unsigned)c;
                best = (key < best) ? key : best;
            }
        }
    }
    const unsigned bidx = (unsigned)(best & 0xFFFFFFFFu);
    if (lane == 0) ids[row] = (float)bidx;
    float4 v = ((const float4*)(cent + (size_t)bidx * D_DIM))[lane];
    ((float4*)(quant + (size_t)row * D_DIM))[lane] = v;
}

// ============================ launch ============================
extern "C" void kernel_launch(void* const* d_in, const int* in_sizes, int n_in,
                              void* d_out, int out_size, void* d_ws, size_t ws_size,
                              hipStream_t stream) {
    const float* feat = (const float*)d_in[0];   // 8192 x 256
    const float* cent = (const float*)d_in[1];   // 16384 x 256

    float* out = (float*)d_out;
    float* quant = out;                 // 2097152
    float* ids   = out + 2097152;       // 8192
    float* dist  = out + 2105344;       // 8192*16384

    char* ws = (char*)d_ws;
    unsigned short* Abf = (unsigned short*)ws;                       // 4MB
    unsigned short* Bbf = (unsigned short*)(ws + (4u << 20));        // 8MB
    float* blockmins    = (float*)(ws + (12u << 20));                // 8MB
    float* xnorm        = (float*)(ws + (20u << 20));                // 32KB
    float* cnorm        = xnorm + N_ROWS;                            // 64KB

    {
        int waves = N_ROWS + K_CENT;
        prep_kernel<<<(waves * 64 + 255) / 256, 256, 0, stream>>>(
            feat, cent, Abf, Bbf, xnorm, cnorm);
    }

    // A-resident streaming GEMM: 64 row-tiles x 8 col-ranges, 512 threads
    dist_stream<<<dim3(N_ROWS / TROWS, 8), 512, 0, stream>>>(
        Abf, Bbf, xnorm, cnorm, dist, blockmins);

    recheck_finalize<<<N_ROWS / 4, 256, 0, stream>>>(
        feat, cent, xnorm, cnorm, blockmins, dist, quant, ids);
}